// Round 1
// baseline (121.836 us; speedup 1.0000x reference)
//
#include <hip/hip_runtime.h>

// Problem constants: N1=N2=512, C=256, H=512. All fp32.
// M[i,j] = b2 + sum_h relu(hx[i,h] + hy[j,h] + b1[h]) * w2[h]
//   hx = (X @ W_sr.T) @ W1x.T   (512x512)
//   hy = (Y @ W_tg.T) @ W1y.T   (512x512), b1 folded in here.

// ---------------------------------------------------------------------------
// GEMM-NT: C[m,n] = sum_k A[m,k]*B[n,k] (+bias[n]).  M=512, K=256 fixed.
// BM=32, BN=64, BK=32. 256 threads. Per-thread 2x4 register tile.
// A staged transposed As[k][m] (stride 34 -> b64 reads 8B-aligned, conflict-free)
// B staged transposed Bs[k][n] (stride 68 -> b128 reads 16B-aligned, 2-way max = free)
// blockIdx.z selects problem 0/1 (X-path / Y-path).
// ---------------------------------------------------------------------------
__global__ __launch_bounds__(256) void gemm_nt(
    const float* __restrict__ A0, const float* __restrict__ A1,
    const float* __restrict__ B0, const float* __restrict__ B1,
    float* __restrict__ C0, float* __restrict__ C1,
    const float* __restrict__ bias1, int N, int ldb)
{
    const int z = blockIdx.z;
    const float* A = z ? A1 : A0;
    const float* B = z ? B1 : B0;
    float* Cc      = z ? C1 : C0;
    const float* bias = z ? bias1 : nullptr;

    __shared__ float As[32 * 34];
    __shared__ float Bs[32 * 68];

    const int t  = threadIdx.x;
    const int m0 = blockIdx.x * 32;
    const int n0 = blockIdx.y * 64;
    const int ti = t / 16;   // 0..15 -> rows {2ti, 2ti+1}
    const int tj = t % 16;   // 0..15 -> cols {4tj..4tj+3} (lane-consecutive = coalesced stores)

    float acc[2][4] = {};

    for (int kt = 0; kt < 256; kt += 32) {
        // stage A tile: 32 m x 32 k, transposed into As[k][m]
        {
            const int m  = t / 8;
            const int k4 = (t % 8) * 4;
            float4 v = *(const float4*)&A[(m0 + m) * 256 + kt + k4];
            As[(k4 + 0) * 34 + m] = v.x;
            As[(k4 + 1) * 34 + m] = v.y;
            As[(k4 + 2) * 34 + m] = v.z;
            As[(k4 + 3) * 34 + m] = v.w;
        }
        // stage B tile: 64 n x 32 k, transposed into Bs[k][n]
        #pragma unroll
        for (int r = 0; r < 2; r++) {
            const int id = t + r * 256;
            const int n  = id / 8;
            const int k4 = (id % 8) * 4;
            float4 v = *(const float4*)&B[(n0 + n) * ldb + kt + k4];
            Bs[(k4 + 0) * 68 + n] = v.x;
            Bs[(k4 + 1) * 68 + n] = v.y;
            Bs[(k4 + 2) * 68 + n] = v.z;
            Bs[(k4 + 3) * 68 + n] = v.w;
        }
        __syncthreads();

        #pragma unroll
        for (int k = 0; k < 32; k++) {
            float2 a = *(float2*)&As[k * 34 + 2 * ti];
            float4 b = *(float4*)&Bs[k * 68 + 4 * tj];
            acc[0][0] += a.x * b.x;  acc[0][1] += a.x * b.y;
            acc[0][2] += a.x * b.z;  acc[0][3] += a.x * b.w;
            acc[1][0] += a.y * b.x;  acc[1][1] += a.y * b.y;
            acc[1][2] += a.y * b.z;  acc[1][3] += a.y * b.w;
        }
        __syncthreads();
    }

    float4 bv = {0.f, 0.f, 0.f, 0.f};
    if (bias) bv = *(const float4*)&bias[n0 + 4 * tj];
    #pragma unroll
    for (int mi = 0; mi < 2; mi++) {
        const int m = m0 + 2 * ti + mi;
        float4 r;
        r.x = acc[mi][0] + bv.x;
        r.y = acc[mi][1] + bv.y;
        r.z = acc[mi][2] + bv.z;
        r.w = acc[mi][3] + bv.w;
        *(float4*)&Cc[m * N + n0 + 4 * tj] = r;
    }
}

// ---------------------------------------------------------------------------
// Core: partial[bz][i][j] = sum_{h in 128-slab bz} relu(hx[i,h]+hy[j,h])*w2[h]
// grid (8,8,4): 64x64 output tile, h split in 4 slabs for occupancy (256 blocks).
// 256 threads, 4x4 register tile (rows ti+16m / cols tj+16n).
// LDS tiles stride 68: b128 compute reads are <=2-way conflicts (free, m136).
// ---------------------------------------------------------------------------
__global__ __launch_bounds__(256) void affinity_core(
    const float* __restrict__ hx, const float* __restrict__ hy,
    const float* __restrict__ w2, float* __restrict__ partial)
{
    __shared__ float xs[64 * 68];
    __shared__ float ys[64 * 68];
    __shared__ float ws2[64];

    const int t  = threadIdx.x;
    const int i0 = blockIdx.x * 64;
    const int j0 = blockIdx.y * 64;
    const int h0 = blockIdx.z * 128;
    const int ti = t / 16;   // 0..15
    const int tj = t % 16;   // 0..15 (lane-consecutive = coalesced partial stores)

    float acc[4][4] = {};

    for (int hc = 0; hc < 128; hc += 64) {
        const int hb = h0 + hc;
        #pragma unroll
        for (int s = 0; s < 4; s++) {
            const int id = t + s * 256;
            const int r  = id / 16;
            const int c4 = (id % 16) * 4;
            *(float4*)&xs[r * 68 + c4] = *(const float4*)&hx[(i0 + r) * 512 + hb + c4];
            *(float4*)&ys[r * 68 + c4] = *(const float4*)&hy[(j0 + r) * 512 + hb + c4];
        }
        if (t < 16) *(float4*)&ws2[t * 4] = *(const float4*)&w2[hb + t * 4];
        __syncthreads();

        #pragma unroll
        for (int h4 = 0; h4 < 16; h4++) {
            float4 w = *(float4*)&ws2[h4 * 4];
            float4 x[4], y[4];
            #pragma unroll
            for (int m = 0; m < 4; m++) x[m] = *(float4*)&xs[(ti + 16 * m) * 68 + h4 * 4];
            #pragma unroll
            for (int n = 0; n < 4; n++) y[n] = *(float4*)&ys[(tj + 16 * n) * 68 + h4 * 4];
            #pragma unroll
            for (int m = 0; m < 4; m++) {
                #pragma unroll
                for (int n = 0; n < 4; n++) {
                    acc[m][n] += fmaxf(x[m].x + y[n].x, 0.f) * w.x
                               + fmaxf(x[m].y + y[n].y, 0.f) * w.y
                               + fmaxf(x[m].z + y[n].z, 0.f) * w.z
                               + fmaxf(x[m].w + y[n].w, 0.f) * w.w;
                }
            }
        }
        __syncthreads();
    }

    float* p = partial + blockIdx.z * (512 * 512);
    #pragma unroll
    for (int m = 0; m < 4; m++) {
        #pragma unroll
        for (int n = 0; n < 4; n++) {
            p[(i0 + ti + 16 * m) * 512 + (j0 + tj + 16 * n)] = acc[m][n];
        }
    }
}

// ---------------------------------------------------------------------------
// Final reduce: out = partial[0]+partial[1]+partial[2]+partial[3] + b2
// ---------------------------------------------------------------------------
__global__ __launch_bounds__(256) void reduce4(
    const float* __restrict__ partial, const float* __restrict__ b2,
    float* __restrict__ out)
{
    const int idx = (blockIdx.x * 256 + threadIdx.x) * 4;
    float4 p0 = *(const float4*)&partial[idx];
    float4 p1 = *(const float4*)&partial[262144 + idx];
    float4 p2 = *(const float4*)&partial[524288 + idx];
    float4 p3 = *(const float4*)&partial[786432 + idx];
    const float bb = b2[0];
    float4 r;
    r.x = p0.x + p1.x + p2.x + p3.x + bb;
    r.y = p0.y + p1.y + p2.y + p3.y + bb;
    r.z = p0.z + p1.z + p2.z + p3.z + bb;
    r.w = p0.w + p1.w + p2.w + p3.w + bb;
    *(float4*)&out[idx] = r;
}

extern "C" void kernel_launch(void* const* d_in, const int* in_sizes, int n_in,
                              void* d_out, int out_size, void* d_ws, size_t ws_size,
                              hipStream_t stream) {
    const float* X    = (const float*)d_in[0];  // 512x256
    const float* Y    = (const float*)d_in[1];  // 512x256
    const float* W_sr = (const float*)d_in[2];  // 256x256
    const float* W_tg = (const float*)d_in[3];  // 256x256
    const float* W1   = (const float*)d_in[4];  // 512x512 (H x 2C)
    const float* b1   = (const float*)d_in[5];  // 512
    const float* w2   = (const float*)d_in[6];  // 1x512
    const float* b2   = (const float*)d_in[7];  // 1

    float* ws      = (float*)d_ws;
    float* Xp      = ws;             // 512*256
    float* Yp      = ws + 131072;    // 512*256
    float* hx      = ws + 262144;    // 512*512
    float* hy      = ws + 524288;    // 512*512
    float* partial = ws + 786432;    // 4 * 512*512
    float* out     = (float*)d_out;

    // Stage 1: Xp = X @ W_sr.T ; Yp = Y @ W_tg.T   (M=512,N=256,K=256)
    gemm_nt<<<dim3(16, 4, 2), 256, 0, stream>>>(X, Y, W_sr, W_tg, Xp, Yp,
                                                nullptr, 256, 256);
    // Stage 2: hx = Xp @ W1x.T ; hy = Yp @ W1y.T + b1  (M=512,N=512,K=256)
    gemm_nt<<<dim3(16, 8, 2), 256, 0, stream>>>(Xp, Yp, W1, W1 + 256, hx, hy,
                                                b1, 512, 512);
    // Stage 3: h-split relu reduction into 4 partials
    affinity_core<<<dim3(8, 8, 4), 256, 0, stream>>>(hx, hy, w2, partial);
    // Stage 4: sum partials + b2
    reduce4<<<256, 256, 0, stream>>>(partial, b2, out);
}

// Round 2
// 116.333 us; speedup vs baseline: 1.0473x; 1.0473x over previous
//
#include <hip/hip_runtime.h>

// Problem constants: N1=N2=512, C=256, H=512. All fp32.
// M[i,j] = b2 + sum_h relu(hx[i,h] + hy[j,h] + b1[h]) * w2[h]
//   hx = (X @ W_sr.T) @ W1x.T   (512x512)
//   hy = (Y @ W_tg.T) @ W1y.T   (512x512), b1 folded in here.

// ---------------------------------------------------------------------------
// GEMM-NT: C[m,n] = sum_k A[m,k]*B[n,k] (+bias[n]).  M=512, K=256 fixed.
// BM=32, BN=64, BK=32. 256 threads. Per-thread 2x4 register tile.
// blockIdx.z selects problem 0/1 (X-path / Y-path).
// ---------------------------------------------------------------------------
__global__ __launch_bounds__(256) void gemm_nt(
    const float* __restrict__ A0, const float* __restrict__ A1,
    const float* __restrict__ B0, const float* __restrict__ B1,
    float* __restrict__ C0, float* __restrict__ C1,
    const float* __restrict__ bias1, int N, int ldb)
{
    const int z = blockIdx.z;
    const float* A = z ? A1 : A0;
    const float* B = z ? B1 : B0;
    float* Cc      = z ? C1 : C0;
    const float* bias = z ? bias1 : nullptr;

    __shared__ float As[32 * 34];
    __shared__ float Bs[32 * 68];

    const int t  = threadIdx.x;
    const int m0 = blockIdx.x * 32;
    const int n0 = blockIdx.y * 64;
    const int ti = t / 16;   // 0..15 -> rows {2ti, 2ti+1}
    const int tj = t % 16;   // 0..15 -> cols {4tj..4tj+3}

    float acc[2][4] = {};

    for (int kt = 0; kt < 256; kt += 32) {
        {
            const int m  = t / 8;
            const int k4 = (t % 8) * 4;
            float4 v = *(const float4*)&A[(m0 + m) * 256 + kt + k4];
            As[(k4 + 0) * 34 + m] = v.x;
            As[(k4 + 1) * 34 + m] = v.y;
            As[(k4 + 2) * 34 + m] = v.z;
            As[(k4 + 3) * 34 + m] = v.w;
        }
        #pragma unroll
        for (int r = 0; r < 2; r++) {
            const int id = t + r * 256;
            const int n  = id / 8;
            const int k4 = (id % 8) * 4;
            float4 v = *(const float4*)&B[(n0 + n) * ldb + kt + k4];
            Bs[(k4 + 0) * 68 + n] = v.x;
            Bs[(k4 + 1) * 68 + n] = v.y;
            Bs[(k4 + 2) * 68 + n] = v.z;
            Bs[(k4 + 3) * 68 + n] = v.w;
        }
        __syncthreads();

        #pragma unroll 8
        for (int k = 0; k < 32; k++) {
            float2 a = *(float2*)&As[k * 34 + 2 * ti];
            float4 b = *(float4*)&Bs[k * 68 + 4 * tj];
            acc[0][0] += a.x * b.x;  acc[0][1] += a.x * b.y;
            acc[0][2] += a.x * b.z;  acc[0][3] += a.x * b.w;
            acc[1][0] += a.y * b.x;  acc[1][1] += a.y * b.y;
            acc[1][2] += a.y * b.z;  acc[1][3] += a.y * b.w;
        }
        __syncthreads();
    }

    float4 bv = {0.f, 0.f, 0.f, 0.f};
    if (bias) bv = *(const float4*)&bias[n0 + 4 * tj];
    #pragma unroll
    for (int mi = 0; mi < 2; mi++) {
        const int m = m0 + 2 * ti + mi;
        float4 r;
        r.x = acc[mi][0] + bv.x;
        r.y = acc[mi][1] + bv.y;
        r.z = acc[mi][2] + bv.z;
        r.w = acc[mi][3] + bv.w;
        *(float4*)&Cc[m * N + n0 + 4 * tj] = r;
    }
}

// ---------------------------------------------------------------------------
// Core: partial[bz][i][j] = sum_{h in 64-slab bz} relu(hx[i,h]+hy[j,h])*w2[h]
// grid (8,8,8): 64x64 output tile x 64-wide h slab -> 512 blocks = 2/CU
// (2 waves/SIMD). 256 threads, 4x4 register tile. Single LDS load phase,
// one barrier. h4 loop unroll-limited to 2 to keep VGPR < 128 (R1: full
// unroll -> 256 VGPR + 34 MB scratch spill traffic -> 134 us).
// LDS stride 68: compute reads are broadcast (x) or 2-way (y) = free (m136).
// ---------------------------------------------------------------------------
__global__ __launch_bounds__(256) void affinity_core(
    const float* __restrict__ hx, const float* __restrict__ hy,
    const float* __restrict__ w2, float* __restrict__ partial)
{
    __shared__ float xs[64 * 68];
    __shared__ float ys[64 * 68];
    __shared__ float ws2[64];

    const int t  = threadIdx.x;
    const int i0 = blockIdx.x * 64;
    const int j0 = blockIdx.y * 64;
    const int h0 = blockIdx.z * 64;
    const int ti = t / 16;   // 0..15
    const int tj = t % 16;   // 0..15

    // Stage: 64 rows x 64 h for both hx and hy (each thread: 4 float4 each)
    #pragma unroll
    for (int s = 0; s < 4; s++) {
        const int id = t + s * 256;
        const int r  = id / 16;
        const int c4 = (id % 16) * 4;
        *(float4*)&xs[r * 68 + c4] = *(const float4*)&hx[(i0 + r) * 512 + h0 + c4];
        *(float4*)&ys[r * 68 + c4] = *(const float4*)&hy[(j0 + r) * 512 + h0 + c4];
    }
    if (t < 16) *(float4*)&ws2[t * 4] = *(const float4*)&w2[h0 + t * 4];
    __syncthreads();

    float acc[4][4] = {};
    const float* xr = xs + ti * 68;
    const float* yr = ys + tj * 68;

    #pragma unroll 2
    for (int h4 = 0; h4 < 16; h4++) {
        const int ho = h4 * 4;
        float4 w = *(const float4*)&ws2[ho];
        float4 x[4], y[4];
        #pragma unroll
        for (int m = 0; m < 4; m++) x[m] = *(const float4*)&xr[m * (16 * 68) + ho];
        #pragma unroll
        for (int n = 0; n < 4; n++) y[n] = *(const float4*)&yr[n * (16 * 68) + ho];
        #pragma unroll
        for (int m = 0; m < 4; m++) {
            #pragma unroll
            for (int n = 0; n < 4; n++) {
                acc[m][n] += fmaxf(x[m].x + y[n].x, 0.f) * w.x
                           + fmaxf(x[m].y + y[n].y, 0.f) * w.y
                           + fmaxf(x[m].z + y[n].z, 0.f) * w.z
                           + fmaxf(x[m].w + y[n].w, 0.f) * w.w;
            }
        }
    }

    float* p = partial + blockIdx.z * (512 * 512);
    #pragma unroll
    for (int m = 0; m < 4; m++) {
        #pragma unroll
        for (int n = 0; n < 4; n++) {
            p[(i0 + ti + 16 * m) * 512 + (j0 + tj + 16 * n)] = acc[m][n];
        }
    }
}

// ---------------------------------------------------------------------------
// Final reduce: out = sum_{s<8} partial[s] + b2
// ---------------------------------------------------------------------------
__global__ __launch_bounds__(256) void reduce8(
    const float* __restrict__ partial, const float* __restrict__ b2,
    float* __restrict__ out)
{
    const int idx = (blockIdx.x * 256 + threadIdx.x) * 4;
    const float bb = b2[0];
    float4 r = {bb, bb, bb, bb};
    #pragma unroll
    for (int s = 0; s < 8; s++) {
        float4 p = *(const float4*)&partial[s * 262144 + idx];
        r.x += p.x; r.y += p.y; r.z += p.z; r.w += p.w;
    }
    *(float4*)&out[idx] = r;
}

extern "C" void kernel_launch(void* const* d_in, const int* in_sizes, int n_in,
                              void* d_out, int out_size, void* d_ws, size_t ws_size,
                              hipStream_t stream) {
    const float* X    = (const float*)d_in[0];  // 512x256
    const float* Y    = (const float*)d_in[1];  // 512x256
    const float* W_sr = (const float*)d_in[2];  // 256x256
    const float* W_tg = (const float*)d_in[3];  // 256x256
    const float* W1   = (const float*)d_in[4];  // 512x512 (H x 2C)
    const float* b1   = (const float*)d_in[5];  // 512
    const float* w2   = (const float*)d_in[6];  // 1x512
    const float* b2   = (const float*)d_in[7];  // 1

    float* ws      = (float*)d_ws;
    float* Xp      = ws;             // 512*256
    float* Yp      = ws + 131072;    // 512*256
    float* hx      = ws + 262144;    // 512*512
    float* hy      = ws + 524288;    // 512*512
    float* partial = ws + 786432;    // 8 * 512*512
    float* out     = (float*)d_out;

    // Stage 1: Xp = X @ W_sr.T ; Yp = Y @ W_tg.T   (M=512,N=256,K=256)
    gemm_nt<<<dim3(16, 4, 2), 256, 0, stream>>>(X, Y, W_sr, W_tg, Xp, Yp,
                                                nullptr, 256, 256);
    // Stage 2: hx = Xp @ W1x.T ; hy = Yp @ W1y.T + b1  (M=512,N=512,K=256)
    gemm_nt<<<dim3(16, 8, 2), 256, 0, stream>>>(Xp, Yp, W1, W1 + 256, hx, hy,
                                                b1, 512, 512);
    // Stage 3: h-split relu reduction into 8 partials (512 blocks = 2/CU)
    affinity_core<<<dim3(8, 8, 8), 256, 0, stream>>>(hx, hy, w2, partial);
    // Stage 4: sum partials + b2
    reduce8<<<256, 256, 0, stream>>>(partial, b2, out);
}